// Round 2
// baseline (449.178 us; speedup 1.0000x reference)
//
#include <hip/hip_runtime.h>

#define NN 10000
#define NE 160000

#define INV8   0.35355339059327373f   // 1/sqrt(8)
#define QINV   0.125f                 // 1/sqrt(64)
#define GAIN   1.679177f
#define ISQ3   0.57735026918962576f   // 1/sqrt(3)
#define FINALS 4.8828125e-5f          // 0.1 * (1/sqrt(512)) * (1/sqrt(128)) * 0.125
#define MPSC   2.2097086912079612e-4f // 0.01 / sqrt(2048)

__device__ __forceinline__ float4 ld4(const float* p){ return *(const float4*)p; }
__device__ __forceinline__ void st4f(float* p, float a, float b, float c, float d){
  float4 t; t.x=a; t.y=b; t.z=c; t.w=d; *(float4*)p = t;
}
__device__ __forceinline__ float sil(float x){ return x*GAIN/(1.f+__expf(-x)); }
#define C4(v,i) (((const float*)&(v))[i])

// Per-node packed records (quad-major, 48 floats per u-quad, 16 quads = 768 floats):
//   S-record[n][uq]: [0:4]=l1s  [4:16]=l1v(3 planes)  [16:20]=qA_lo [20:24]=qA_hi(*1/sqrt3)
//                    [24:36]=rA_lo(3 planes,*1/sqrt3) [36:48]=rA_hi(3 planes,*1/sqrt3)
//   R-record[n][uq]: same with l2s/l2v/qB/rB.

__global__ __launch_bounds__(256) void node_kernel(
    const float* __restrict__ nf, const float* __restrict__ ff,
    const float* __restrict__ W1s, const float* __restrict__ W1v,
    const float* __restrict__ W2s, const float* __restrict__ W2v,
    const float* __restrict__ Wvss, const float* __restrict__ Wvsv,
    const float* __restrict__ Wvrs, const float* __restrict__ Wvrv,
    const float* __restrict__ Wfs0, const float* __restrict__ Wfs1,
    const float* __restrict__ Wfr0, const float* __restrict__ Wfr1,
    const float* __restrict__ Wmsv, const float* __restrict__ Wmvs,
    float* __restrict__ wsS, float* __restrict__ wsR,
    float* __restrict__ out)
{
  const int lane = threadIdx.x & 63;
  const int Wid  = blockIdx.x * 4 + (threadIdx.x >> 6);
  const int p    = __builtin_amdgcn_readfirstlane(Wid & 7);   // wave-uniform part id
  const int grp  = __builtin_amdgcn_readfirstlane(Wid >> 3);
  const int n = grp * 64 + lane;
  if (n >= NN) return;
  const float* nrow = nf + (size_t)n * 256;
  const int vb = p * 8;
  const size_t rec = (size_t)n * 768;

  // ---------- P1: l1s/l2s/l1v/l2v for v in [vb, vb+8) ----------
  float a1s[8], a2s[8], a1v[3][8], a2v[3][8], t1[16];
  #pragma unroll
  for (int j = 0; j < 8; ++j){ a1s[j]=0.f; a2s[j]=0.f;
    a1v[0][j]=0.f; a1v[1][j]=0.f; a1v[2][j]=0.f;
    a2v[0][j]=0.f; a2v[1][j]=0.f; a2v[2][j]=0.f; }
  #pragma unroll
  for (int j = 0; j < 16; ++j) t1[j]=0.f;

  for (int u = 0; u < 64; ++u) {
    const float su  = nrow[u];
    const float nv0 = nrow[64+u*3+0];
    const float nv1 = nrow[64+u*3+1];
    const float nv2 = nrow[64+u*3+2];
    const float4 s1a = ld4(W1s+u*64+vb), s1b = ld4(W1s+u*64+vb+4);
    const float4 s2a = ld4(W2s+u*64+vb), s2b = ld4(W2s+u*64+vb+4);
    const float4 v1a = ld4(W1v+u*64+vb), v1b = ld4(W1v+u*64+vb+4);
    const float4 v2a = ld4(W2v+u*64+vb), v2b = ld4(W2v+u*64+vb+4);
    #pragma unroll
    for (int d = 0; d < 4; ++d) {
      a1s[d]     += su*C4(s1a,d);  a1s[4+d]     += su*C4(s1b,d);
      a2s[d]     += su*C4(s2a,d);  a2s[4+d]     += su*C4(s2b,d);
      a1v[0][d]  += nv0*C4(v1a,d); a1v[0][4+d]  += nv0*C4(v1b,d);
      a1v[1][d]  += nv1*C4(v1a,d); a1v[1][4+d]  += nv1*C4(v1b,d);
      a1v[2][d]  += nv2*C4(v1a,d); a1v[2][4+d]  += nv2*C4(v1b,d);
      a2v[0][d]  += nv0*C4(v2a,d); a2v[0][4+d]  += nv0*C4(v2b,d);
      a2v[1][d]  += nv1*C4(v2a,d); a2v[1][4+d]  += nv1*C4(v2b,d);
      a2v[2][d]  += nv2*C4(v2a,d); a2v[2][4+d]  += nv2*C4(v2b,d);
    }
    if (p == 0) {
      #pragma unroll
      for (int q = 0; q < 4; ++q) {
        const float4 m = ld4(Wmsv + u*16 + q*4);
        t1[q*4]   += su*m.x; t1[q*4+1] += su*m.y;
        t1[q*4+2] += su*m.z; t1[q*4+3] += su*m.w;
      }
    }
  }
  #pragma unroll
  for (int hh = 0; hh < 2; ++hh) {
    const int uq = 2*p + hh, o = hh*4;
    float* S = wsS + rec + uq*48;
    float* R = wsR + rec + uq*48;
    st4f(S+0,  a1s[o]*QINV, a1s[o+1]*QINV, a1s[o+2]*QINV, a1s[o+3]*QINV);
    st4f(S+4,  a1v[0][o]*QINV, a1v[0][o+1]*QINV, a1v[0][o+2]*QINV, a1v[0][o+3]*QINV);
    st4f(S+8,  a1v[1][o]*QINV, a1v[1][o+1]*QINV, a1v[1][o+2]*QINV, a1v[1][o+3]*QINV);
    st4f(S+12, a1v[2][o]*QINV, a1v[2][o+1]*QINV, a1v[2][o+2]*QINV, a1v[2][o+3]*QINV);
    st4f(R+0,  a2s[o]*QINV, a2s[o+1]*QINV, a2s[o+2]*QINV, a2s[o+3]*QINV);
    st4f(R+4,  a2v[0][o]*QINV, a2v[0][o+1]*QINV, a2v[0][o+2]*QINV, a2v[0][o+3]*QINV);
    st4f(R+8,  a2v[1][o]*QINV, a2v[1][o+1]*QINV, a2v[1][o+2]*QINV, a2v[1][o+3]*QINV);
    st4f(R+12, a2v[2][o]*QINV, a2v[2][o+1]*QINV, a2v[2][o+2]*QINV, a2v[2][o+3]*QINV);
  }

  // ---------- field vectors ----------
  float fsv[16], fvv[48];
  {
    const float* fr = ff + (size_t)n*64;
    #pragma unroll
    for (int q = 0; q < 4; ++q) {
      const float4 t = ld4(fr + q*4);
      fsv[q*4]=t.x; fsv[q*4+1]=t.y; fsv[q*4+2]=t.z; fsv[q*4+3]=t.w;
    }
    #pragma unroll
    for (int q = 0; q < 12; ++q) {
      const float4 t = ld4(fr + 16 + q*4);
      fvv[q*4]=t.x; fvv[q*4+1]=t.y; fvv[q*4+2]=t.z; fvv[q*4+3]=t.w;
    }
  }

  // ---------- multipoles (mp1 only; mp0 is overwritten by charges) ----------
  if (p == 0) {
    float m0=0.f, m1=0.f, m2=0.f;
    #pragma unroll
    for (int v = 0; v < 16; ++v) {
      m0 += t1[v]*fvv[v*3]; m1 += t1[v]*fvv[v*3+1]; m2 += t1[v]*fvv[v*3+2];
    }
    for (int u = 0; u < 64; ++u) {
      float t2 = 0.f;
      #pragma unroll
      for (int q = 0; q < 4; ++q) {
        const float4 w = ld4(Wmvs + u*16 + q*4);
        t2 += w.x*fsv[q*4] + w.y*fsv[q*4+1] + w.z*fsv[q*4+2] + w.w*fsv[q*4+3];
      }
      m0 += nrow[64+u*3+0]*t2;
      m1 += nrow[64+u*3+1]*t2;
      m2 += nrow[64+u*3+2]*t2;
    }
    float* o = out + (size_t)n*4;
    o[0] = 0.f;                         // charges accumulated by edge kernel
    o[1] = MPSC*m0; o[2] = MPSC*m1; o[3] = MPSC*m2;
  }

  // ---------- gs/gv: field projected through Wfs/Wfr ----------
  float gsA[16], gsB[16], gvA[48], gvB[48];
  #pragma unroll
  for (int up = 0; up < 16; ++up) {
    float sA=0.f,sB=0.f,vA0=0.f,vA1=0.f,vA2=0.f,vB0=0.f,vB1=0.f,vB2=0.f;
    #pragma unroll
    for (int q = 0; q < 4; ++q) {
      const float4 w0 = ld4(Wfs0 + up*16 + q*4);
      const float4 w1 = ld4(Wfs1 + up*16 + q*4);
      const float4 w2 = ld4(Wfr0 + up*16 + q*4);
      const float4 w3 = ld4(Wfr1 + up*16 + q*4);
      #pragma unroll
      for (int d = 0; d < 4; ++d) {
        const int v = q*4+d;
        sA  += C4(w0,d)*fsv[v];
        sB  += C4(w2,d)*fsv[v];
        vA0 += C4(w1,d)*fvv[v*3]; vA1 += C4(w1,d)*fvv[v*3+1]; vA2 += C4(w1,d)*fvv[v*3+2];
        vB0 += C4(w3,d)*fvv[v*3]; vB1 += C4(w3,d)*fvv[v*3+1]; vB2 += C4(w3,d)*fvv[v*3+2];
      }
    }
    gsA[up]=sA; gsB[up]=sB;
    gvA[up*3]=vA0; gvA[up*3+1]=vA1; gvA[up*3+2]=vA2;
    gvB[up*3]=vB0; gvB[up*3+1]=vB1; gvB[up*3+2]=vB2;
  }

  // ---------- q/r tables for U in [p*16, p*16+16) ----------
  #pragma unroll
  for (int tq = 0; tq < 4; ++tq) {
    float qa[4], qb[4], ra[3][4], rb[3][4];
    #pragma unroll
    for (int d = 0; d < 4; ++d) {
      const int U = p*16 + tq*4 + d;
      float aq=0.f,bq=0.f,a0=0.f,a1=0.f,a2=0.f,b0=0.f,b1=0.f,b2=0.f;
      #pragma unroll
      for (int q = 0; q < 4; ++q) {
        const float4 ws_ = ld4(Wvss + U*16 + q*4);
        const float4 wr_ = ld4(Wvrs + U*16 + q*4);
        const float4 wv_ = ld4(Wvsv + U*16 + q*4);
        const float4 wu_ = ld4(Wvrv + U*16 + q*4);
        #pragma unroll
        for (int dd = 0; dd < 4; ++dd) {
          const int up = q*4+dd;
          aq += C4(ws_,dd)*gsA[up];
          bq += C4(wr_,dd)*gsB[up];
          a0 += C4(wv_,dd)*gvA[up*3]; a1 += C4(wv_,dd)*gvA[up*3+1]; a2 += C4(wv_,dd)*gvA[up*3+2];
          b0 += C4(wu_,dd)*gvB[up*3]; b1 += C4(wu_,dd)*gvB[up*3+1]; b2 += C4(wu_,dd)*gvB[up*3+2];
        }
      }
      qa[d]=aq; qb[d]=bq;
      ra[0][d]=a0*ISQ3; ra[1][d]=a1*ISQ3; ra[2][d]=a2*ISQ3;
      rb[0][d]=b0*ISQ3; rb[1][d]=b1*ISQ3; rb[2][d]=b2*ISQ3;
    }
    if (p < 4) {                      // U < 64 : lo slots
      const int uq = p*4 + tq;
      float* S = wsS + rec + uq*48;
      float* R = wsR + rec + uq*48;
      st4f(S+16, qa[0],qa[1],qa[2],qa[3]);
      st4f(S+24, ra[0][0],ra[0][1],ra[0][2],ra[0][3]);
      st4f(S+28, ra[1][0],ra[1][1],ra[1][2],ra[1][3]);
      st4f(S+32, ra[2][0],ra[2][1],ra[2][2],ra[2][3]);
      st4f(R+16, qb[0],qb[1],qb[2],qb[3]);
      st4f(R+24, rb[0][0],rb[0][1],rb[0][2],rb[0][3]);
      st4f(R+28, rb[1][0],rb[1][1],rb[1][2],rb[1][3]);
      st4f(R+32, rb[2][0],rb[2][1],rb[2][2],rb[2][3]);
    } else {                          // U >= 64 : hi slots, qa gets 1/sqrt3 (m11 fold)
      const int uq = (p-4)*4 + tq;
      float* S = wsS + rec + uq*48;
      float* R = wsR + rec + uq*48;
      st4f(S+20, qa[0]*ISQ3,qa[1]*ISQ3,qa[2]*ISQ3,qa[3]*ISQ3);
      st4f(S+36, ra[0][0],ra[0][1],ra[0][2],ra[0][3]);
      st4f(S+40, ra[1][0],ra[1][1],ra[1][2],ra[1][3]);
      st4f(S+44, ra[2][0],ra[2][1],ra[2][2],ra[2][3]);
      st4f(R+20, qb[0]*ISQ3,qb[1]*ISQ3,qb[2]*ISQ3,qb[3]*ISQ3);
      st4f(R+36, rb[0][0],rb[0][1],rb[0][2],rb[0][3]);
      st4f(R+40, rb[1][0],rb[1][1],rb[1][2],rb[1][3]);
      st4f(R+44, rb[2][0],rb[2][1],rb[2][2],rb[2][3]);
    }
  }
}

// ---------------- edge kernel: thread-per-edge, uniform weight reads ----------------
__global__ __launch_bounds__(256) void edge_kernel(
    const float* __restrict__ ea, const float* __restrict__ efe,
    const int* __restrict__ eidx,
    const float* __restrict__ mw1, const float* __restrict__ mw2,
    const float* __restrict__ mw3, const float* __restrict__ mw4,
    const float* __restrict__ wsS, const float* __restrict__ wsR,
    float* __restrict__ out)
{
  __shared__ float hl[64*256];          // per-thread h column, no barriers needed
  const int tid = threadIdx.x;
  const int e = blockIdx.x * 256 + tid; // grid is exactly 625*256 = NE
  const int s = eidx[e];
  const int r = eidx[NE + e];
  const float4 y = ld4(ea + (size_t)e*4);   // y0, y1[0..2]
  float ef[8];
  {
    const float4 a = ld4(efe + (size_t)e*8);
    const float4 b = ld4(efe + (size_t)e*8 + 4);
    ef[0]=a.x; ef[1]=a.y; ef[2]=a.z; ef[3]=a.w;
    ef[4]=b.x; ef[5]=b.y; ef[6]=b.z; ef[7]=b.w;
  }

  float acc[64];
  // ---- L1: 8 -> 64 ----
  #pragma unroll
  for (int j = 0; j < 64; ++j) acc[j] = 0.f;
  #pragma unroll
  for (int k = 0; k < 8; ++k) {
    const float* row = mw1 + k*64;
    #pragma unroll
    for (int q = 0; q < 16; ++q) {
      const float4 w = ld4(row + q*4);
      acc[q*4]   += ef[k]*w.x; acc[q*4+1] += ef[k]*w.y;
      acc[q*4+2] += ef[k]*w.z; acc[q*4+3] += ef[k]*w.w;
    }
  }
  #pragma unroll
  for (int j = 0; j < 64; ++j) hl[j*256+tid] = sil(acc[j]*INV8);

  // ---- L2: 64 -> 64 ----
  #pragma unroll
  for (int j = 0; j < 64; ++j) acc[j] = 0.f;
  for (int k = 0; k < 64; ++k) {
    const float hk = hl[k*256+tid];
    const float* row = mw2 + k*64;
    #pragma unroll
    for (int q = 0; q < 16; ++q) {
      const float4 w = ld4(row + q*4);
      acc[q*4]   += hk*w.x; acc[q*4+1] += hk*w.y;
      acc[q*4+2] += hk*w.z; acc[q*4+3] += hk*w.w;
    }
  }
  #pragma unroll
  for (int j = 0; j < 64; ++j) hl[j*256+tid] = sil(acc[j]*QINV);

  // ---- L3: 64 -> 64 ----
  #pragma unroll
  for (int j = 0; j < 64; ++j) acc[j] = 0.f;
  for (int k = 0; k < 64; ++k) {
    const float hk = hl[k*256+tid];
    const float* row = mw3 + k*64;
    #pragma unroll
    for (int q = 0; q < 16; ++q) {
      const float4 w = ld4(row + q*4);
      acc[q*4]   += hk*w.x; acc[q*4+1] += hk*w.y;
      acc[q*4+2] += hk*w.z; acc[q*4+3] += hk*w.w;
    }
  }
  #pragma unroll
  for (int j = 0; j < 64; ++j) hl[j*256+tid] = sil(acc[j]*QINV);

  // ---- L4 (64 -> 4x64, per u-quad) fused with combine + p contraction ----
  float accS = 0.f, accR = 0.f;
  const float* Sbase = wsS + (size_t)s*768;
  const float* Rbase = wsR + (size_t)r*768;
  for (int uq = 0; uq < 16; ++uq) {
    const float* Sr = Sbase + uq*48;
    const float* Rr = Rbase + uq*48;
    // gathers issued first to overlap with the w4 dot products
    const float4 bsS=ld4(Sr+0),  sv0=ld4(Sr+4),  sv1=ld4(Sr+8),  sv2=ld4(Sr+12);
    const float4 qa0=ld4(Sr+16), qa1=ld4(Sr+20);
    const float4 ra00=ld4(Sr+24),ra01=ld4(Sr+28),ra02=ld4(Sr+32);
    const float4 ra10=ld4(Sr+36),ra11=ld4(Sr+40),ra12=ld4(Sr+44);
    const float4 bsR=ld4(Rr+0),  rv0=ld4(Rr+4),  rv1=ld4(Rr+8),  rv2=ld4(Rr+12);
    const float4 qb0=ld4(Rr+16), qb1=ld4(Rr+20);
    const float4 rb00=ld4(Rr+24),rb01=ld4(Rr+28),rb02=ld4(Rr+32);
    const float4 rb10=ld4(Rr+36),rb11=ld4(Rr+40),rb12=ld4(Rr+44);

    float wq[16];
    #pragma unroll
    for (int j = 0; j < 16; ++j) wq[j] = 0.f;
    const float* w4b = mw4 + uq*4;
    for (int k = 0; k < 64; ++k) {
      const float hk = hl[k*256+tid];
      const float* row = w4b + k*256;
      const float4 c0 = ld4(row), c1 = ld4(row+64), c2 = ld4(row+128), c3 = ld4(row+192);
      wq[0] +=hk*c0.x; wq[1] +=hk*c0.y; wq[2] +=hk*c0.z; wq[3] +=hk*c0.w;
      wq[4] +=hk*c1.x; wq[5] +=hk*c1.y; wq[6] +=hk*c1.z; wq[7] +=hk*c1.w;
      wq[8] +=hk*c2.x; wq[9] +=hk*c2.y; wq[10]+=hk*c2.z; wq[11]+=hk*c2.w;
      wq[12]+=hk*c3.x; wq[13]+=hk*c3.y; wq[14]+=hk*c3.z; wq[15]+=hk*c3.w;
    }
    #pragma unroll
    for (int d = 0; d < 4; ++d) {
      const float bs = C4(bsS,d) + C4(bsR,d);
      const float b0 = C4(sv0,d) + C4(rv0,d);
      const float b1 = C4(sv1,d) + C4(rv1,d);
      const float b2 = C4(sv2,d) + C4(rv2,d);
      const float bvy = b0*y.y + b1*y.z + b2*y.w;
      const float m0 = wq[d]    * bs * y.x;
      const float m1 = wq[4+d]  * bvy;
      const float m2 = wq[8+d]  * bs;
      const float m3 = wq[12+d] * y.x;
      accS += m0*C4(qa0,d) + m1*C4(qa1,d)
            + m2*(y.y*C4(ra00,d) + y.z*C4(ra01,d) + y.w*C4(ra02,d))
            + m3*(b0*C4(ra10,d) + b1*C4(ra11,d) + b2*C4(ra12,d));
      accR += m0*C4(qb0,d) + m1*C4(qb1,d)
            + m2*(y.y*C4(rb00,d) + y.z*C4(rb01,d) + y.w*C4(rb02,d))
            + m3*(b0*C4(rb10,d) + b1*C4(rb11,d) + b2*C4(rb12,d));
    }
  }
  const float pj = FINALS * (accS + accR);
  out[NN*4 + e] = pj;
  atomicAdd(out + (size_t)r*4, pj);
  atomicAdd(out + (size_t)s*4, -pj);
}

extern "C" void kernel_launch(void* const* d_in, const int* in_sizes, int n_in,
                              void* d_out, int out_size, void* d_ws, size_t ws_size,
                              hipStream_t stream) {
  (void)in_sizes; (void)n_in; (void)out_size; (void)ws_size;
  const float* node_feats  = (const float*)d_in[1];
  const float* edge_attrs  = (const float*)d_in[2];
  const float* edge_feats  = (const float*)d_in[3];
  const float* field_feats = (const float*)d_in[4];
  const int*   edge_index  = (const int*)  d_in[5];
  const float* W1s  = (const float*)d_in[6];
  const float* W1v  = (const float*)d_in[7];
  const float* W2s  = (const float*)d_in[8];
  const float* W2v  = (const float*)d_in[9];
  const float* mw1  = (const float*)d_in[10];
  const float* mw2  = (const float*)d_in[11];
  const float* mw3  = (const float*)d_in[12];
  const float* mw4  = (const float*)d_in[13];
  const float* Wvss = (const float*)d_in[14];
  const float* Wvsv = (const float*)d_in[15];
  const float* Wvrs = (const float*)d_in[16];
  const float* Wvrv = (const float*)d_in[17];
  const float* Wfs0 = (const float*)d_in[18];
  const float* Wfs1 = (const float*)d_in[19];
  const float* Wfr0 = (const float*)d_in[20];
  const float* Wfr1 = (const float*)d_in[21];
  // d_in[22] (Wmp_ss) and d_in[23] (Wmp_vv) feed only mp0, which the reference
  // overwrites with charges -> unused.
  const float* Wmsv = (const float*)d_in[24];
  const float* Wmvs = (const float*)d_in[25];

  float* out = (float*)d_out;
  float* wsS = (float*)d_ws;                 // 10000*768 floats
  float* wsR = wsS + (size_t)NN*768;         // 10000*768 floats (total 61.44 MB)

  hipLaunchKernelGGL(node_kernel, dim3(314), dim3(256), 0, stream,
      node_feats, field_feats, W1s, W1v, W2s, W2v, Wvss, Wvsv, Wvrs, Wvrv,
      Wfs0, Wfs1, Wfr0, Wfr1, Wmsv, Wmvs, wsS, wsR, out);
  hipLaunchKernelGGL(edge_kernel, dim3(625), dim3(256), 0, stream,
      edge_attrs, edge_feats, edge_index, mw1, mw2, mw3, mw4, wsS, wsR, out);
}